// Round 1
// baseline (853.916 us; speedup 1.0000x reference)
//
#include <hip/hip_runtime.h>
#include <math.h>

#define NB   8
#define SS   1024
#define DD   512
#define HH   8
#define DKK  64
#define NEGF (-3.0e38f)

// ---------------------------------------------------------------------------
// GEMM1: q = x @ Wk^T + bk ; v = x @ Wv^T + bv, written as [b,h,s,dk]
// C[m,n] = sum_k X[m,k] * W[n,k] + b[n];  M=8192, N=1024 (0..511 q, 512..1023 v)
// BM=BN=64, BK=16, 256 threads, 4x4 microtile.
// ---------------------------------------------------------------------------
__global__ __launch_bounds__(256) void gemm_qv(
    const float* __restrict__ x,
    const float* __restrict__ Wk, const float* __restrict__ bk,
    const float* __restrict__ Wv, const float* __restrict__ bv,
    float* __restrict__ q_ws, float* __restrict__ v_ws)
{
    __shared__ __align__(16) float As[16][68];
    __shared__ __align__(16) float Bs[16][68];
    const int m0 = blockIdx.x * 64;
    const int n0 = blockIdx.y * 64;
    const bool is_v = (n0 >= DD);
    const float* __restrict__ Wp = is_v ? Wv : Wk;
    const float* __restrict__ bp = is_v ? bv : bk;
    const int nw = n0 & (DD - 1);   // row offset within W

    const int t  = threadIdx.x;
    const int lr = t >> 2;          // 0..63 load row
    const int lc = (t & 3) * 4;     // 0,4,8,12 load col (k)
    const int mi = (t & 15) * 4;    // microtile row
    const int ni = (t >> 4) * 4;    // microtile col

    float c[4][4] = {};

    for (int k0 = 0; k0 < DD; k0 += 16) {
        __syncthreads();
        float4 a = *(const float4*)&x[(size_t)(m0 + lr) * DD + k0 + lc];
        As[lc + 0][lr] = a.x; As[lc + 1][lr] = a.y;
        As[lc + 2][lr] = a.z; As[lc + 3][lr] = a.w;
        float4 bb = *(const float4*)&Wp[(size_t)(nw + lr) * DD + k0 + lc];
        Bs[lc + 0][lr] = bb.x; Bs[lc + 1][lr] = bb.y;
        Bs[lc + 2][lr] = bb.z; Bs[lc + 3][lr] = bb.w;
        __syncthreads();
        #pragma unroll
        for (int kk = 0; kk < 16; ++kk) {
            float4 a4 = *(const float4*)&As[kk][mi];
            float4 b4 = *(const float4*)&Bs[kk][ni];
            c[0][0] = fmaf(a4.x, b4.x, c[0][0]); c[0][1] = fmaf(a4.x, b4.y, c[0][1]);
            c[0][2] = fmaf(a4.x, b4.z, c[0][2]); c[0][3] = fmaf(a4.x, b4.w, c[0][3]);
            c[1][0] = fmaf(a4.y, b4.x, c[1][0]); c[1][1] = fmaf(a4.y, b4.y, c[1][1]);
            c[1][2] = fmaf(a4.y, b4.z, c[1][2]); c[1][3] = fmaf(a4.y, b4.w, c[1][3]);
            c[2][0] = fmaf(a4.z, b4.x, c[2][0]); c[2][1] = fmaf(a4.z, b4.y, c[2][1]);
            c[2][2] = fmaf(a4.z, b4.z, c[2][2]); c[2][3] = fmaf(a4.z, b4.w, c[2][3]);
            c[3][0] = fmaf(a4.w, b4.x, c[3][0]); c[3][1] = fmaf(a4.w, b4.y, c[3][1]);
            c[3][2] = fmaf(a4.w, b4.z, c[3][2]); c[3][3] = fmaf(a4.w, b4.w, c[3][3]);
        }
    }

    float4 bias = *(const float4*)&bp[nw + ni];
    const int h = nw >> 6;          // head index (n0 is 64-aligned, so ni<64 is dk)
    float* __restrict__ dst = is_v ? v_ws : q_ws;
    #pragma unroll
    for (int u = 0; u < 4; ++u) {
        const int m    = m0 + mi + u;
        const int bidx = m >> 10;
        const int srow = m & (SS - 1);
        float4 r = make_float4(c[u][0] + bias.x, c[u][1] + bias.y,
                               c[u][2] + bias.z, c[u][3] + bias.w);
        *(float4*)&dst[((size_t)(bidx * HH + h) * SS + srow) * DKK + ni] = r;
    }
}

// ---------------------------------------------------------------------------
// GEMM2: out = attn @ Wo^T + bo.  attn is [b,s,h*dk] = [m][512] row-major.
// ---------------------------------------------------------------------------
__global__ __launch_bounds__(256) void gemm_out(
    const float* __restrict__ A,
    const float* __restrict__ Wo, const float* __restrict__ bo,
    float* __restrict__ out)
{
    __shared__ __align__(16) float As[16][68];
    __shared__ __align__(16) float Bs[16][68];
    const int m0 = blockIdx.x * 64;
    const int n0 = blockIdx.y * 64;

    const int t  = threadIdx.x;
    const int lr = t >> 2;
    const int lc = (t & 3) * 4;
    const int mi = (t & 15) * 4;
    const int ni = (t >> 4) * 4;

    float c[4][4] = {};

    for (int k0 = 0; k0 < DD; k0 += 16) {
        __syncthreads();
        float4 a = *(const float4*)&A[(size_t)(m0 + lr) * DD + k0 + lc];
        As[lc + 0][lr] = a.x; As[lc + 1][lr] = a.y;
        As[lc + 2][lr] = a.z; As[lc + 3][lr] = a.w;
        float4 bb = *(const float4*)&Wo[(size_t)(n0 + lr) * DD + k0 + lc];
        Bs[lc + 0][lr] = bb.x; Bs[lc + 1][lr] = bb.y;
        Bs[lc + 2][lr] = bb.z; Bs[lc + 3][lr] = bb.w;
        __syncthreads();
        #pragma unroll
        for (int kk = 0; kk < 16; ++kk) {
            float4 a4 = *(const float4*)&As[kk][mi];
            float4 b4 = *(const float4*)&Bs[kk][ni];
            c[0][0] = fmaf(a4.x, b4.x, c[0][0]); c[0][1] = fmaf(a4.x, b4.y, c[0][1]);
            c[0][2] = fmaf(a4.x, b4.z, c[0][2]); c[0][3] = fmaf(a4.x, b4.w, c[0][3]);
            c[1][0] = fmaf(a4.y, b4.x, c[1][0]); c[1][1] = fmaf(a4.y, b4.y, c[1][1]);
            c[1][2] = fmaf(a4.y, b4.z, c[1][2]); c[1][3] = fmaf(a4.y, b4.w, c[1][3]);
            c[2][0] = fmaf(a4.z, b4.x, c[2][0]); c[2][1] = fmaf(a4.z, b4.y, c[2][1]);
            c[2][2] = fmaf(a4.z, b4.z, c[2][2]); c[2][3] = fmaf(a4.z, b4.w, c[2][3]);
            c[3][0] = fmaf(a4.w, b4.x, c[3][0]); c[3][1] = fmaf(a4.w, b4.y, c[3][1]);
            c[3][2] = fmaf(a4.w, b4.z, c[3][2]); c[3][3] = fmaf(a4.w, b4.w, c[3][3]);
        }
    }

    float4 bias = *(const float4*)&bo[n0 + ni];
    #pragma unroll
    for (int u = 0; u < 4; ++u) {
        const int m = m0 + mi + u;
        float4 r = make_float4(c[u][0] + bias.x, c[u][1] + bias.y,
                               c[u][2] + bias.z, c[u][3] + bias.w);
        *(float4*)&out[(size_t)m * DD + n0 + ni] = r;
    }
}

// ---------------------------------------------------------------------------
// Fused attention: one wave per row i of one (b,h). Scores in 16 regs/lane
// (lane holds j = 64*t + lane). Two softmaxes + prefix-sum distance decay,
// all row-local. k == q (kq_same). attn out layout: [b, s, h, dk].
// ---------------------------------------------------------------------------
__global__ __launch_bounds__(256) void attn_kernel(
    const float* __restrict__ q,      // [B,H,S,DK]
    const float* __restrict__ v,      // [B,H,S,DK]
    const float* __restrict__ utT,    // [B,S,S]
    const float* __restrict__ gammas, // [H]
    float* __restrict__ attn)         // [B,S,H,DK]
{
    __shared__ __align__(16) float k_lds[64][66];   // [j][dk], stride 66
    __shared__ __align__(16) float p_buf[4][64];

    const int tid  = threadIdx.x;
    const int w    = tid >> 6;
    const int lane = tid & 63;
    const int bh   = blockIdx.y;
    const int b    = bh >> 3;
    const int h    = bh & 7;
    const int i    = blockIdx.x * 4 + w;

    const float* __restrict__ kq = q + (size_t)bh * SS * DKK;
    const float* __restrict__ vp = v + (size_t)bh * SS * DKK;
    const float* __restrict__ ut_row = utT + ((size_t)b * SS + i) * SS;

    // rows in a block never straddle a 64-boundary (4*bx..4*bx+3), so the
    // tile count is block-uniform -> barriers below are uniform.
    const int ntiles = (blockIdx.x * 4 + 3) / 64 + 1;

    // q row i -> registers (wave-uniform broadcast loads)
    float qr[DKK];
    {
        const float* qrow = &kq[(size_t)i * DKK];
        #pragma unroll
        for (int d4 = 0; d4 < 16; ++d4) {
            float4 tq = *(const float4*)&qrow[d4 * 4];
            qr[d4 * 4 + 0] = tq.x; qr[d4 * 4 + 1] = tq.y;
            qr[d4 * 4 + 2] = tq.z; qr[d4 * 4 + 3] = tq.w;
        }
    }

    float sreg[16];
    #pragma unroll
    for (int tt = 0; tt < 16; ++tt) sreg[tt] = NEGF;

    // ---- Phase 1: raw scores = (q.k)/8 * utT, causal-masked ----
    #pragma unroll
    for (int tt = 0; tt < 16; ++tt) {
        const bool active = (tt < ntiles);     // block-uniform
        if (active) {
            const int j0 = tt * 64;
            __syncthreads();
            {   // stage K tile [64][64] -> LDS (coalesced float4 reads)
                const int r0 = tid >> 4;          // 0..15
                const int c4 = (tid & 15) * 4;    // 0..60
                #pragma unroll
                for (int rep = 0; rep < 4; ++rep) {
                    const int r = r0 + rep * 16;
                    float4 kv = *(const float4*)&kq[(size_t)(j0 + r) * DKK + c4];
                    *(float2*)&k_lds[r][c4]     = make_float2(kv.x, kv.y);
                    *(float2*)&k_lds[r][c4 + 2] = make_float2(kv.z, kv.w);
                }
            }
            __syncthreads();
            const int j = j0 + lane;
            if (j <= i) {
                float ac0 = 0.f, ac1 = 0.f, ac2 = 0.f, ac3 = 0.f;
                #pragma unroll
                for (int d8 = 0; d8 < 8; ++d8) {
                    const int d = d8 * 8;
                    float2 ka = *(const float2*)&k_lds[lane][d];
                    float2 kb = *(const float2*)&k_lds[lane][d + 2];
                    float2 kc = *(const float2*)&k_lds[lane][d + 4];
                    float2 kd = *(const float2*)&k_lds[lane][d + 6];
                    ac0 = fmaf(qr[d + 0], ka.x, ac0); ac0 = fmaf(qr[d + 1], ka.y, ac0);
                    ac1 = fmaf(qr[d + 2], kb.x, ac1); ac1 = fmaf(qr[d + 3], kb.y, ac1);
                    ac2 = fmaf(qr[d + 4], kc.x, ac2); ac2 = fmaf(qr[d + 5], kc.y, ac2);
                    ac3 = fmaf(qr[d + 6], kd.x, ac3); ac3 = fmaf(qr[d + 7], kd.y, ac3);
                }
                const float dot = (ac0 + ac1) + (ac2 + ac3);
                sreg[tt] = dot * 0.125f * ut_row[j];
            }
        }
    }

    // ---- first softmax stats ----
    float m1 = NEGF;
    #pragma unroll
    for (int tt = 0; tt < 16; ++tt) m1 = fmaxf(m1, sreg[tt]);
    #pragma unroll
    for (int o = 32; o >= 1; o >>= 1) m1 = fmaxf(m1, __shfl_xor(m1, o));

    float ee[16];
    float z1 = 0.f;
    #pragma unroll
    for (int tt = 0; tt < 16; ++tt) {
        const int j = tt * 64 + lane;
        ee[tt] = (j <= i) ? __expf(sreg[tt] - m1) : 0.f;
        z1 += ee[tt];
    }
    #pragma unroll
    for (int o = 32; o >= 1; o >>= 1) z1 += __shfl_xor(z1, o);
    const float inv_z1 = 1.0f / z1;

    // ---- Phase 2: prefix sum -> distance decay -> new scores (into ee) ----
    const float g     = gammas[h];
    const float gamma = -log1pf(__expf(g));   // -softplus

    float carry = 0.f;
    float m2 = NEGF;
    #pragma unroll
    for (int tt = 0; tt < 16; ++tt) {
        float xv = ee[tt];
        #pragma unroll
        for (int o = 1; o < 64; o <<= 1) {   // Hillis-Steele inclusive scan
            float y = __shfl_up(xv, (unsigned)o);
            if (lane >= o) xv += y;
        }
        const float tile_tot = __shfl(xv, 63);
        const float csum = (carry + xv) * inv_z1;   // normalized inclusive cumsum
        carry += tile_tot;

        const int j = tt * 64 + lane;
        const float pe = (float)(i - j);            // |i-j| for valid j<=i
        const float dd = fmaxf((1.0f - csum) * pe, 0.0f);
        float te = __expf(sqrtf(dd) * gamma);
        te = fminf(fmaxf(te, 1e-5f), 1e5f);
        const float nsv = (j <= i) ? sreg[tt] * te : NEGF;
        ee[tt] = nsv;
        m2 = fmaxf(m2, nsv);
    }
    #pragma unroll
    for (int o = 32; o >= 1; o >>= 1) m2 = fmaxf(m2, __shfl_xor(m2, o));

    float z2 = 0.f;
    #pragma unroll
    for (int tt = 0; tt < 16; ++tt) {
        ee[tt] = __expf(ee[tt] - m2);   // NEGF - m2 -> exp -> 0 for invalid
        z2 += ee[tt];
    }
    #pragma unroll
    for (int o = 32; o >= 1; o >>= 1) z2 += __shfl_xor(z2, o);
    const float inv_z2 = 1.0f / z2;
    #pragma unroll
    for (int tt = 0; tt < 16; ++tt) ee[tt] *= inv_z2;   // final probabilities

    // ---- Phase 3: O[d] = sum_j p_j * v[j][d]; lane = d ----
    float oa0 = 0.f, oa1 = 0.f, oa2 = 0.f, oa3 = 0.f;
    #pragma unroll
    for (int tt = 0; tt < 16; ++tt) {
        if (tt < ntiles) {                      // block-uniform
            __syncthreads();
            p_buf[w][lane] = ee[tt];
            __syncthreads();
            const float* vrow = &vp[(size_t)(tt * 64) * DKK + lane];
            #pragma unroll
            for (int j4 = 0; j4 < 16; ++j4) {
                float4 p4 = *(const float4*)&p_buf[w][j4 * 4];
                float acc = (j4 & 1) ? oa1 : oa0;  // rotate chains for ILP
                acc = fmaf(p4.x, vrow[(size_t)(j4 * 4 + 0) * DKK], acc);
                acc = fmaf(p4.y, vrow[(size_t)(j4 * 4 + 1) * DKK], acc);
                if (j4 & 1) oa1 = acc; else oa0 = acc;
                float acc2 = (j4 & 1) ? oa3 : oa2;
                acc2 = fmaf(p4.z, vrow[(size_t)(j4 * 4 + 2) * DKK], acc2);
                acc2 = fmaf(p4.w, vrow[(size_t)(j4 * 4 + 3) * DKK], acc2);
                if (j4 & 1) oa3 = acc2; else oa2 = acc2;
            }
        }
    }
    const float o_acc = (oa0 + oa1) + (oa2 + oa3);
    attn[(((size_t)b * SS + i) * HH + h) * DKK + lane] = o_acc;
}

// ---------------------------------------------------------------------------
extern "C" void kernel_launch(void* const* d_in, const int* in_sizes, int n_in,
                              void* d_out, int out_size, void* d_ws, size_t ws_size,
                              hipStream_t stream) {
    const float* x      = (const float*)d_in[0];
    const float* utT    = (const float*)d_in[1];
    const float* Wk     = (const float*)d_in[2];
    const float* bk     = (const float*)d_in[3];
    const float* Wv     = (const float*)d_in[4];
    const float* bv     = (const float*)d_in[5];
    const float* Wo     = (const float*)d_in[6];
    const float* bo     = (const float*)d_in[7];
    const float* gammas = (const float*)d_in[8];
    float* out = (float*)d_out;

    const size_t per = (size_t)NB * HH * SS * DKK;  // 4,194,304 floats
    float* q_ws    = (float*)d_ws;
    float* v_ws    = q_ws + per;
    float* attn_ws = v_ws + per;

    dim3 blk(256);
    dim3 g1(128, 16);
    gemm_qv<<<g1, blk, 0, stream>>>(x, Wk, bk, Wv, bv, q_ws, v_ws);

    dim3 g2(SS / 4, NB * HH);
    attn_kernel<<<g2, blk, 0, stream>>>(q_ws, v_ws, utT, gammas, attn_ws);

    dim3 g3(128, 8);
    gemm_out<<<g3, blk, 0, stream>>>(attn_ws, Wo, bo, out);
}

// Round 4
// 583.088 us; speedup vs baseline: 1.4645x; 1.4645x over previous
//
#include <hip/hip_runtime.h>
#include <math.h>

#define NB   8
#define SS   1024
#define DD   512
#define HH   8
#define DKK  64
#define NEGF (-3.0e38f)

// LDS strides (elements). R3->R4 BUGFIX: K/V/Q strides were SMALLER than the
// 64-half row (48/46) -> adjacent staged rows overlapped and clobbered each
// other's heads. Strides must be >= 64 halves:
#define QSTR 72    // halves; 144 B row, 16B-aligned b128 A-frags
#define KSTR 72    // halves; 144 B row, 16B-aligned b128 B-frags, even bank spread
#define VSTR 66    // halves; u16 B-frag gathers: quads hit disjoint 8-bank groups
#define SSTR 260   // floats
#define PSTR 264   // halves; 528 B row, 16B-aligned b128 A-frags

typedef _Float16 half8 __attribute__((ext_vector_type(8)));
typedef float    f32x4 __attribute__((ext_vector_type(4)));

// ---------------------------------------------------------------------------
// GEMM1: q = x @ Wk^T + bk ; v = x @ Wv^T + bv, written as [b,h,s,dk] (fp32)
// ---------------------------------------------------------------------------
__global__ __launch_bounds__(256) void gemm_qv(
    const float* __restrict__ x,
    const float* __restrict__ Wk, const float* __restrict__ bk,
    const float* __restrict__ Wv, const float* __restrict__ bv,
    float* __restrict__ q_ws, float* __restrict__ v_ws)
{
    __shared__ __align__(16) float As[16][68];
    __shared__ __align__(16) float Bs[16][68];
    const int m0 = blockIdx.x * 64;
    const int n0 = blockIdx.y * 64;
    const bool is_v = (n0 >= DD);
    const float* __restrict__ Wp = is_v ? Wv : Wk;
    const float* __restrict__ bp = is_v ? bv : bk;
    const int nw = n0 & (DD - 1);

    const int t  = threadIdx.x;
    const int lr = t >> 2;
    const int lc = (t & 3) * 4;
    const int mi = (t & 15) * 4;
    const int ni = (t >> 4) * 4;

    float c[4][4] = {};

    for (int k0 = 0; k0 < DD; k0 += 16) {
        __syncthreads();
        float4 a = *(const float4*)&x[(size_t)(m0 + lr) * DD + k0 + lc];
        As[lc + 0][lr] = a.x; As[lc + 1][lr] = a.y;
        As[lc + 2][lr] = a.z; As[lc + 3][lr] = a.w;
        float4 bb = *(const float4*)&Wp[(size_t)(nw + lr) * DD + k0 + lc];
        Bs[lc + 0][lr] = bb.x; Bs[lc + 1][lr] = bb.y;
        Bs[lc + 2][lr] = bb.z; Bs[lc + 3][lr] = bb.w;
        __syncthreads();
        #pragma unroll
        for (int kk = 0; kk < 16; ++kk) {
            float4 a4 = *(const float4*)&As[kk][mi];
            float4 b4 = *(const float4*)&Bs[kk][ni];
            c[0][0] = fmaf(a4.x, b4.x, c[0][0]); c[0][1] = fmaf(a4.x, b4.y, c[0][1]);
            c[0][2] = fmaf(a4.x, b4.z, c[0][2]); c[0][3] = fmaf(a4.x, b4.w, c[0][3]);
            c[1][0] = fmaf(a4.y, b4.x, c[1][0]); c[1][1] = fmaf(a4.y, b4.y, c[1][1]);
            c[1][2] = fmaf(a4.y, b4.z, c[1][2]); c[1][3] = fmaf(a4.y, b4.w, c[1][3]);
            c[2][0] = fmaf(a4.z, b4.x, c[2][0]); c[2][1] = fmaf(a4.z, b4.y, c[2][1]);
            c[2][2] = fmaf(a4.z, b4.z, c[2][2]); c[2][3] = fmaf(a4.z, b4.w, c[2][3]);
            c[3][0] = fmaf(a4.w, b4.x, c[3][0]); c[3][1] = fmaf(a4.w, b4.y, c[3][1]);
            c[3][2] = fmaf(a4.w, b4.z, c[3][2]); c[3][3] = fmaf(a4.w, b4.w, c[3][3]);
        }
    }

    float4 bias = *(const float4*)&bp[nw + ni];
    const int h = nw >> 6;
    float* __restrict__ dst = is_v ? v_ws : q_ws;
    #pragma unroll
    for (int u = 0; u < 4; ++u) {
        const int m    = m0 + mi + u;
        const int bidx = m >> 10;
        const int srow = m & (SS - 1);
        float4 r = make_float4(c[u][0] + bias.x, c[u][1] + bias.y,
                               c[u][2] + bias.z, c[u][3] + bias.w);
        *(float4*)&dst[((size_t)(bidx * HH + h) * SS + srow) * DKK + ni] = r;
    }
}

// ---------------------------------------------------------------------------
// GEMM2: out = attn @ Wo^T + bo (fp32)
// ---------------------------------------------------------------------------
__global__ __launch_bounds__(256) void gemm_out(
    const float* __restrict__ A,
    const float* __restrict__ Wo, const float* __restrict__ bo,
    float* __restrict__ out)
{
    __shared__ __align__(16) float As[16][68];
    __shared__ __align__(16) float Bs[16][68];
    const int m0 = blockIdx.x * 64;
    const int n0 = blockIdx.y * 64;

    const int t  = threadIdx.x;
    const int lr = t >> 2;
    const int lc = (t & 3) * 4;
    const int mi = (t & 15) * 4;
    const int ni = (t >> 4) * 4;

    float c[4][4] = {};

    for (int k0 = 0; k0 < DD; k0 += 16) {
        __syncthreads();
        float4 a = *(const float4*)&A[(size_t)(m0 + lr) * DD + k0 + lc];
        As[lc + 0][lr] = a.x; As[lc + 1][lr] = a.y;
        As[lc + 2][lr] = a.z; As[lc + 3][lr] = a.w;
        float4 bb = *(const float4*)&Wo[(size_t)(n0 + lr) * DD + k0 + lc];
        Bs[lc + 0][lr] = bb.x; Bs[lc + 1][lr] = bb.y;
        Bs[lc + 2][lr] = bb.z; Bs[lc + 3][lr] = bb.w;
        __syncthreads();
        #pragma unroll
        for (int kk = 0; kk < 16; ++kk) {
            float4 a4 = *(const float4*)&As[kk][mi];
            float4 b4 = *(const float4*)&Bs[kk][ni];
            c[0][0] = fmaf(a4.x, b4.x, c[0][0]); c[0][1] = fmaf(a4.x, b4.y, c[0][1]);
            c[0][2] = fmaf(a4.x, b4.z, c[0][2]); c[0][3] = fmaf(a4.x, b4.w, c[0][3]);
            c[1][0] = fmaf(a4.y, b4.x, c[1][0]); c[1][1] = fmaf(a4.y, b4.y, c[1][1]);
            c[1][2] = fmaf(a4.y, b4.z, c[1][2]); c[1][3] = fmaf(a4.y, b4.w, c[1][3]);
            c[2][0] = fmaf(a4.z, b4.x, c[2][0]); c[2][1] = fmaf(a4.z, b4.y, c[2][1]);
            c[2][2] = fmaf(a4.z, b4.z, c[2][2]); c[2][3] = fmaf(a4.z, b4.w, c[2][3]);
            c[3][0] = fmaf(a4.w, b4.x, c[3][0]); c[3][1] = fmaf(a4.w, b4.y, c[3][1]);
            c[3][2] = fmaf(a4.w, b4.z, c[3][2]); c[3][3] = fmaf(a4.w, b4.w, c[3][3]);
        }
    }

    float4 bias = *(const float4*)&bo[n0 + ni];
    #pragma unroll
    for (int u = 0; u < 4; ++u) {
        const int m = m0 + mi + u;
        float4 r = make_float4(c[u][0] + bias.x, c[u][1] + bias.y,
                               c[u][2] + bias.z, c[u][3] + bias.w);
        *(float4*)&out[(size_t)m * DD + n0 + ni] = r;
    }
}

// ---------------------------------------------------------------------------
// MFMA attention. Block = 1024 thr (16 waves) = 16 q-rows of one (b,h).
// j chunked in 256-col slabs. Wave w: (a) stages K/V j-tile w, (b) MFMAs
// score j-tile w, (c) owns row r0+w for the scalar softmax/scan phases.
// Waves 0..3 do the PV MFMA (ntile = w).
// ---------------------------------------------------------------------------
__global__ __launch_bounds__(1024) void attn_mfma(
    const float* __restrict__ q,      // [B,H,S,DK] fp32
    const float* __restrict__ v,      // [B,H,S,DK] fp32
    const float* __restrict__ utT,    // [B,S,S]
    const float* __restrict__ gammas, // [H]
    float* __restrict__ attn)         // [B,S,H,DK] fp32
{
    __shared__ __align__(16) _Float16 kv_lds[256 * KSTR]; // 36864 B (V: 256*VSTR=33792 B fits)
    __shared__ __align__(16) float    s_lds[16 * SSTR];   // 16640 B (p_lds aliases: 8448 B)
    __shared__ __align__(16) _Float16 q_lds[16 * QSTR];   // 2304 B

    _Float16* p_lds = (_Float16*)s_lds;

    const int tid  = threadIdx.x;
    const int w    = tid >> 6;
    const int lane = tid & 63;
    const int quad = lane >> 4;
    const int n    = lane & 15;
    const int bh   = blockIdx.y;
    const int b    = bh >> 3;
    const int h    = bh & 7;
    const int r0   = blockIdx.x * 16;

    const float* __restrict__ kq = q + (size_t)bh * SS * DKK;
    const float* __restrict__ vp = v + (size_t)bh * SS * DKK;

    const int nchunk = (r0 + 16 + 255) >> 8;   // block-uniform, 1..4
    const int nt     = nchunk * 4;             // valid 64-wide tiles per row

    // staging lane mapping: 4 lanes per row, 64B contiguous per lane per iter
    const int srow = lane >> 2;    // 0..15 row within j-tile
    const int scol = lane & 3;     // float4 group

    // ---- stage Q rows r0..r0+15 (fp32 -> fp16) ----
    if (tid < 256) {
        const int row = tid >> 4;
        const int c   = tid & 15;
        float4 f = *(const float4*)&kq[(size_t)(r0 + row) * DKK + c * 4];
        _Float16* dst = &q_lds[row * QSTR + c * 4];
        dst[0] = (_Float16)f.x; dst[1] = (_Float16)f.y;
        dst[2] = (_Float16)f.z; dst[3] = (_Float16)f.w;
    }

    float sreg[16];
    #pragma unroll
    for (int t2 = 0; t2 < 16; ++t2) sreg[t2] = NEGF;

    // ================= Phase 1: scores via MFMA =================
    #pragma unroll
    for (int c0 = 0; c0 < 4; ++c0) {
        if (c0 < nchunk) {
            const int j0 = c0 * 256;
            __syncthreads();
            // stage K j-tile w if any of its rows are causally needed
            if (j0 + w * 16 <= r0 + 15) {
                const float* gsrc = &kq[(size_t)(j0 + w * 16 + srow) * DKK];
                _Float16* ldst = &kv_lds[(w * 16 + srow) * KSTR];
                #pragma unroll
                for (int c = 0; c < 4; ++c) {
                    const int d0 = scol * 4 + c * 16;
                    float4 f = *(const float4*)&gsrc[d0];
                    ldst[d0 + 0] = (_Float16)f.x; ldst[d0 + 1] = (_Float16)f.y;
                    ldst[d0 + 2] = (_Float16)f.z; ldst[d0 + 3] = (_Float16)f.w;
                }
            }
            __syncthreads();
            // wave w computes score j-tile jt = w
            {
                const int jbase = j0 + w * 16;
                if (jbase <= r0 + 15) {
                    f32x4 d = {0.f, 0.f, 0.f, 0.f};
                    #pragma unroll
                    for (int ks = 0; ks < 2; ++ks) {
                        half8 a  = *(const half8*)&q_lds[n * QSTR + ks * 32 + quad * 8];
                        half8 bb = *(const half8*)&kv_lds[(w * 16 + n) * KSTR + ks * 32 + quad * 8];
                        d = __builtin_amdgcn_mfma_f32_16x16x32_f16(a, bb, d, 0, 0, 0);
                    }
                    const int j = jbase + n;
                    #pragma unroll
                    for (int reg = 0; reg < 4; ++reg) {
                        const int i = r0 + quad * 4 + reg;
                        float val = NEGF;
                        if (j <= i)
                            val = d[reg] * 0.125f * utT[((size_t)b * SS + i) * SS + j];
                        s_lds[(quad * 4 + reg) * SSTR + w * 16 + n] = val;
                    }
                } else {
                    #pragma unroll
                    for (int reg = 0; reg < 4; ++reg)
                        s_lds[(quad * 4 + reg) * SSTR + w * 16 + n] = NEGF;
                }
            }
            __syncthreads();
            // row-wave w pulls its 256 scores into registers
            #pragma unroll
            for (int ttl = 0; ttl < 4; ++ttl)
                sreg[c0 * 4 + ttl] = s_lds[w * SSTR + ttl * 64 + lane];
        }
    }

    // ================= Phase 2: scalar softmax / scan / decay (row = r0+w) ===
    const int i_row = r0 + w;

    float m1 = NEGF;
    #pragma unroll
    for (int t2 = 0; t2 < 16; ++t2) if (t2 < nt) m1 = fmaxf(m1, sreg[t2]);
    #pragma unroll
    for (int o = 32; o >= 1; o >>= 1) m1 = fmaxf(m1, __shfl_xor(m1, o));

    float ee[16];
    float z1 = 0.f;
    #pragma unroll
    for (int t2 = 0; t2 < 16; ++t2) {
        float e = 0.f;
        if (t2 < nt) {
            const int j = t2 * 64 + lane;
            if (j <= i_row) e = __expf(sreg[t2] - m1);
        }
        ee[t2] = e;
        z1 += e;
    }
    #pragma unroll
    for (int o = 32; o >= 1; o >>= 1) z1 += __shfl_xor(z1, o);
    const float inv_z1 = 1.0f / z1;

    const float g     = gammas[h];
    const float gamma = -log1pf(__expf(g));   // -softplus

    float carry = 0.f;
    float m2 = NEGF;
    #pragma unroll
    for (int t2 = 0; t2 < 16; ++t2) {
        if (t2 < nt) {
            float xv = ee[t2];
            #pragma unroll
            for (int o = 1; o < 64; o <<= 1) {
                float y = __shfl_up(xv, (unsigned)o);
                if (lane >= o) xv += y;
            }
            const float tile_tot = __shfl(xv, 63);
            const float csum = (carry + xv) * inv_z1;
            carry += tile_tot;

            const int j = t2 * 64 + lane;
            const float pe = (float)(i_row - j);
            const float dd = fmaxf((1.0f - csum) * pe, 0.0f);
            float te = __expf(sqrtf(dd) * gamma);
            te = fminf(fmaxf(te, 1e-5f), 1e5f);
            const float nsv = (j <= i_row) ? sreg[t2] * te : NEGF;
            ee[t2] = nsv;
            m2 = fmaxf(m2, nsv);
        }
    }
    #pragma unroll
    for (int o = 32; o >= 1; o >>= 1) m2 = fmaxf(m2, __shfl_xor(m2, o));

    float z2 = 0.f;
    #pragma unroll
    for (int t2 = 0; t2 < 16; ++t2) {
        if (t2 < nt) {
            ee[t2] = __expf(ee[t2] - m2);
            z2 += ee[t2];
        }
    }
    #pragma unroll
    for (int o = 32; o >= 1; o >>= 1) z2 += __shfl_xor(z2, o);
    const float inv_z2 = 1.0f / z2;
    #pragma unroll
    for (int t2 = 0; t2 < 16; ++t2) if (t2 < nt) ee[t2] *= inv_z2;

    // ================= Phase 3: PV via MFMA =================
    f32x4 oacc = {0.f, 0.f, 0.f, 0.f};
    #pragma unroll
    for (int c0 = 0; c0 < 4; ++c0) {
        if (c0 < nchunk) {
            const int j0 = c0 * 256;
            __syncthreads();   // prior kv_lds / p_lds readers done
            // stage V j-tile w (full tile — garbage-free reads for masked j)
            {
                const float* gsrc = &vp[(size_t)(j0 + w * 16 + srow) * DKK];
                _Float16* ldst = &kv_lds[(w * 16 + srow) * VSTR];
                #pragma unroll
                for (int c = 0; c < 4; ++c) {
                    const int d0 = scol * 4 + c * 16;
                    float4 f = *(const float4*)&gsrc[d0];
                    ldst[d0 + 0] = (_Float16)f.x; ldst[d0 + 1] = (_Float16)f.y;
                    ldst[d0 + 2] = (_Float16)f.z; ldst[d0 + 3] = (_Float16)f.w;
                }
            }
            // row-wave w publishes its p chunk as fp16
            #pragma unroll
            for (int ttl = 0; ttl < 4; ++ttl)
                p_lds[w * PSTR + ttl * 64 + lane] = (_Float16)ee[c0 * 4 + ttl];
            __syncthreads();
            // PV MFMA on waves 0..3 (ntile = w), K-bounded by causality.
            // nkt clamped to 8: non-final chunks need all 8 k-tiles.
            if (w < 4) {
                int nkt = (r0 + 16 - j0 + 31) >> 5;
                nkt = (nkt > 8) ? 8 : nkt;   // 1..8
                for (int kt = 0; kt < nkt; ++kt) {
                    half8 a = *(const half8*)&p_lds[n * PSTR + kt * 32 + quad * 8];
                    half8 bb;
                    #pragma unroll
                    for (int jj = 0; jj < 8; ++jj)
                        bb[jj] = kv_lds[(kt * 32 + quad * 8 + jj) * VSTR + w * 16 + n];
                    oacc = __builtin_amdgcn_mfma_f32_16x16x32_f16(a, bb, oacc, 0, 0, 0);
                }
            }
        }
    }

    if (w < 4) {
        #pragma unroll
        for (int reg = 0; reg < 4; ++reg) {
            const int i = r0 + quad * 4 + reg;
            attn[(((size_t)b * SS + i) * HH + h) * DKK + w * 16 + n] = oacc[reg];
        }
    }
}

// ---------------------------------------------------------------------------
extern "C" void kernel_launch(void* const* d_in, const int* in_sizes, int n_in,
                              void* d_out, int out_size, void* d_ws, size_t ws_size,
                              hipStream_t stream) {
    const float* x      = (const float*)d_in[0];
    const float* utT    = (const float*)d_in[1];
    const float* Wk     = (const float*)d_in[2];
    const float* bk     = (const float*)d_in[3];
    const float* Wv     = (const float*)d_in[4];
    const float* bv     = (const float*)d_in[5];
    const float* Wo     = (const float*)d_in[6];
    const float* bo     = (const float*)d_in[7];
    const float* gammas = (const float*)d_in[8];
    float* out = (float*)d_out;

    const size_t per = (size_t)NB * HH * SS * DKK;  // 4,194,304 floats
    float* q_ws    = (float*)d_ws;
    float* v_ws    = q_ws + per;
    float* attn_ws = v_ws + per;

    dim3 blk(256);
    dim3 g1(128, 16);
    gemm_qv<<<g1, blk, 0, stream>>>(x, Wk, bk, Wv, bv, q_ws, v_ws);

    dim3 g2(SS / 16, NB * HH);
    attn_mfma<<<g2, dim3(1024), 0, stream>>>(q_ws, v_ws, utT, gammas, attn_ws);

    dim3 g3(128, 8);
    gemm_out<<<g3, blk, 0, stream>>>(attn_ws, Wo, bo, out);
}

// Round 5
// 418.784 us; speedup vs baseline: 2.0390x; 1.3923x over previous
//
#include <hip/hip_runtime.h>
#include <math.h>

#define NB   8
#define SS   1024
#define DD   512
#define HH   8
#define DKK  64
#define NEGF (-3.0e38f)

// LDS strides (elements, fp16 unless noted)
#define QSTR 72    // 144 B rows, 16B-aligned b128 A-frags
#define KSTR 72
#define VSTR 72    // 144 B rows; u16 PV gather -> 8 words/wave, broadcast-free
#define SSTR 260   // floats
#define PSTR 264   // 528 B rows, 16B-aligned b128 A-frags
#define WSTR 40    // gemm staging: 80 B rows, 16B-aligned b128 frags, 2-way banks

typedef _Float16 half8 __attribute__((ext_vector_type(8)));
typedef float    f32x4 __attribute__((ext_vector_type(4)));

// ---------------------------------------------------------------------------
// MFMA GEMM #1: q = x@Wk^T + bk ; v = x@Wv^T + bv  -> fp16 [b,h,s,dk]
// 256 thr = 2x2 waves, each wave a 32x32 tile (2x2 of 16x16x32 MFMA), BK=32.
// ---------------------------------------------------------------------------
__global__ __launch_bounds__(256) void gemm_qv(
    const float* __restrict__ x,
    const float* __restrict__ Wk, const float* __restrict__ bk,
    const float* __restrict__ Wv, const float* __restrict__ bv,
    _Float16* __restrict__ q_ws, _Float16* __restrict__ v_ws)
{
    __shared__ __align__(16) _Float16 Asm[64 * WSTR];  // 5120 B
    __shared__ __align__(16) _Float16 Bsm[64 * WSTR];

    const int m0  = blockIdx.x * 64;
    const int n0c = blockIdx.y * 64;          // 0..1023
    const bool is_v = (n0c >= DD);
    const float* __restrict__ Wp = is_v ? Wv : Wk;
    const float* __restrict__ bp = is_v ? bv : bk;
    const int n0 = n0c & (DD - 1);

    const int tid  = threadIdx.x;
    const int w    = tid >> 6;
    const int lane = tid & 63;
    const int quad = lane >> 4;
    const int n    = lane & 15;
    const int wm   = w >> 1, wn = w & 1;

    const int srow = tid >> 2;          // 0..63
    const int sc8  = (tid & 3) * 8;     // 0,8,16,24

    f32x4 acc[2][2] = {{{0.f,0.f,0.f,0.f},{0.f,0.f,0.f,0.f}},
                       {{0.f,0.f,0.f,0.f},{0.f,0.f,0.f,0.f}}};

    for (int k0 = 0; k0 < DD; k0 += 32) {
        __syncthreads();
        {   // stage A slab 64x32 fp32->fp16
            const float* src = &x[(size_t)(m0 + srow) * DD + k0 + sc8];
            float4 f0 = *(const float4*)&src[0];
            float4 f1 = *(const float4*)&src[4];
            half8 hv = {(_Float16)f0.x,(_Float16)f0.y,(_Float16)f0.z,(_Float16)f0.w,
                        (_Float16)f1.x,(_Float16)f1.y,(_Float16)f1.z,(_Float16)f1.w};
            *(half8*)&Asm[srow * WSTR + sc8] = hv;
        }
        {   // stage W slab 64x32 fp32->fp16
            const float* src = &Wp[(size_t)(n0 + srow) * DD + k0 + sc8];
            float4 f0 = *(const float4*)&src[0];
            float4 f1 = *(const float4*)&src[4];
            half8 hv = {(_Float16)f0.x,(_Float16)f0.y,(_Float16)f0.z,(_Float16)f0.w,
                        (_Float16)f1.x,(_Float16)f1.y,(_Float16)f1.z,(_Float16)f1.w};
            *(half8*)&Bsm[srow * WSTR + sc8] = hv;
        }
        __syncthreads();
        half8 a0 = *(const half8*)&Asm[(wm*32 +  0 + n) * WSTR + quad*8];
        half8 a1 = *(const half8*)&Asm[(wm*32 + 16 + n) * WSTR + quad*8];
        half8 b0 = *(const half8*)&Bsm[(wn*32 +  0 + n) * WSTR + quad*8];
        half8 b1 = *(const half8*)&Bsm[(wn*32 + 16 + n) * WSTR + quad*8];
        acc[0][0] = __builtin_amdgcn_mfma_f32_16x16x32_f16(a0, b0, acc[0][0], 0,0,0);
        acc[0][1] = __builtin_amdgcn_mfma_f32_16x16x32_f16(a0, b1, acc[0][1], 0,0,0);
        acc[1][0] = __builtin_amdgcn_mfma_f32_16x16x32_f16(a1, b0, acc[1][0], 0,0,0);
        acc[1][1] = __builtin_amdgcn_mfma_f32_16x16x32_f16(a1, b1, acc[1][1], 0,0,0);
    }

    _Float16* __restrict__ dst = is_v ? v_ws : q_ws;
    const int h = n0 >> 6;   // head (n0 is 64-aligned)
    #pragma unroll
    for (int tm = 0; tm < 2; ++tm) {
        #pragma unroll
        for (int tn = 0; tn < 2; ++tn) {
            const int dk = wn*32 + tn*16 + n;
            const float bias = bp[n0 + dk];
            #pragma unroll
            for (int reg = 0; reg < 4; ++reg) {
                const int grow = m0 + wm*32 + tm*16 + quad*4 + reg;
                const int bidx = grow >> 10;
                const int sr   = grow & (SS - 1);
                dst[((size_t)(bidx * HH + h) * SS + sr) * DKK + dk] =
                    (_Float16)(acc[tm][tn][reg] + bias);
            }
        }
    }
}

// ---------------------------------------------------------------------------
// MFMA GEMM #2: out = attn @ Wo^T + bo (A fp32 -> fp16 staged; out fp32)
// ---------------------------------------------------------------------------
__global__ __launch_bounds__(256) void gemm_out(
    const float* __restrict__ A,
    const float* __restrict__ Wo, const float* __restrict__ bo,
    float* __restrict__ out)
{
    __shared__ __align__(16) _Float16 Asm[64 * WSTR];
    __shared__ __align__(16) _Float16 Bsm[64 * WSTR];

    const int m0 = blockIdx.x * 64;
    const int n0 = blockIdx.y * 64;

    const int tid  = threadIdx.x;
    const int w    = tid >> 6;
    const int lane = tid & 63;
    const int quad = lane >> 4;
    const int n    = lane & 15;
    const int wm   = w >> 1, wn = w & 1;

    const int srow = tid >> 2;
    const int sc8  = (tid & 3) * 8;

    f32x4 acc[2][2] = {{{0.f,0.f,0.f,0.f},{0.f,0.f,0.f,0.f}},
                       {{0.f,0.f,0.f,0.f},{0.f,0.f,0.f,0.f}}};

    for (int k0 = 0; k0 < DD; k0 += 32) {
        __syncthreads();
        {
            const float* src = &A[(size_t)(m0 + srow) * DD + k0 + sc8];
            float4 f0 = *(const float4*)&src[0];
            float4 f1 = *(const float4*)&src[4];
            half8 hv = {(_Float16)f0.x,(_Float16)f0.y,(_Float16)f0.z,(_Float16)f0.w,
                        (_Float16)f1.x,(_Float16)f1.y,(_Float16)f1.z,(_Float16)f1.w};
            *(half8*)&Asm[srow * WSTR + sc8] = hv;
        }
        {
            const float* src = &Wo[(size_t)(n0 + srow) * DD + k0 + sc8];
            float4 f0 = *(const float4*)&src[0];
            float4 f1 = *(const float4*)&src[4];
            half8 hv = {(_Float16)f0.x,(_Float16)f0.y,(_Float16)f0.z,(_Float16)f0.w,
                        (_Float16)f1.x,(_Float16)f1.y,(_Float16)f1.z,(_Float16)f1.w};
            *(half8*)&Bsm[srow * WSTR + sc8] = hv;
        }
        __syncthreads();
        half8 a0 = *(const half8*)&Asm[(wm*32 +  0 + n) * WSTR + quad*8];
        half8 a1 = *(const half8*)&Asm[(wm*32 + 16 + n) * WSTR + quad*8];
        half8 b0 = *(const half8*)&Bsm[(wn*32 +  0 + n) * WSTR + quad*8];
        half8 b1 = *(const half8*)&Bsm[(wn*32 + 16 + n) * WSTR + quad*8];
        acc[0][0] = __builtin_amdgcn_mfma_f32_16x16x32_f16(a0, b0, acc[0][0], 0,0,0);
        acc[0][1] = __builtin_amdgcn_mfma_f32_16x16x32_f16(a0, b1, acc[0][1], 0,0,0);
        acc[1][0] = __builtin_amdgcn_mfma_f32_16x16x32_f16(a1, b0, acc[1][0], 0,0,0);
        acc[1][1] = __builtin_amdgcn_mfma_f32_16x16x32_f16(a1, b1, acc[1][1], 0,0,0);
    }

    #pragma unroll
    for (int tm = 0; tm < 2; ++tm) {
        #pragma unroll
        for (int tn = 0; tn < 2; ++tn) {
            const int col  = n0 + wn*32 + tn*16 + n;
            const float bias = bo[col];
            #pragma unroll
            for (int reg = 0; reg < 4; ++reg) {
                const int grow = m0 + wm*32 + tm*16 + quad*4 + reg;
                out[(size_t)grow * DD + col] = acc[tm][tn][reg] + bias;
            }
        }
    }
}

// ---------------------------------------------------------------------------
// MFMA attention (q, v now fp16). Structure unchanged from R4.
// ---------------------------------------------------------------------------
__global__ __launch_bounds__(1024) void attn_mfma(
    const _Float16* __restrict__ q,   // [B,H,S,DK] fp16
    const _Float16* __restrict__ v,   // [B,H,S,DK] fp16
    const float* __restrict__ utT,    // [B,S,S]
    const float* __restrict__ gammas, // [H]
    float* __restrict__ attn)         // [B,S,H,DK] fp32
{
    __shared__ __align__(16) _Float16 kv_lds[256 * KSTR]; // 36864 B
    __shared__ __align__(16) float    s_lds[16 * SSTR];   // 16640 B (p_lds aliases)
    __shared__ __align__(16) _Float16 q_lds[16 * QSTR];   // 2304 B

    _Float16* p_lds = (_Float16*)s_lds;

    const int tid  = threadIdx.x;
    const int w    = tid >> 6;
    const int lane = tid & 63;
    const int quad = lane >> 4;
    const int n    = lane & 15;
    const int bh   = blockIdx.y;
    const int b    = bh >> 3;
    const int h    = bh & 7;
    const int r0   = blockIdx.x * 16;

    const _Float16* __restrict__ kq = q + (size_t)bh * SS * DKK;
    const _Float16* __restrict__ vp = v + (size_t)bh * SS * DKK;

    const int nchunk = (r0 + 16 + 255) >> 8;   // 1..4, block-uniform
    const int nt     = nchunk * 4;

    const int srow = lane >> 2;    // 0..15 row within j-tile
    const int scol = lane & 3;     // 16-half group

    // ---- stage Q rows (fp16 copy) ----
    if (tid < 256) {
        const int row = tid >> 4;
        const int c   = tid & 15;
        *(uint2*)&q_lds[row * QSTR + c * 4] =
            *(const uint2*)&kq[(size_t)(r0 + row) * DKK + c * 4];
    }

    float sreg[16];
    #pragma unroll
    for (int t2 = 0; t2 < 16; ++t2) sreg[t2] = NEGF;

    // ================= Phase 1: scores via MFMA =================
    #pragma unroll
    for (int c0 = 0; c0 < 4; ++c0) {
        if (c0 < nchunk) {
            const int j0 = c0 * 256;
            __syncthreads();
            if (j0 + w * 16 <= r0 + 15) {   // stage K j-tile w (fp16 copy)
                const _Float16* gsrc = &kq[(size_t)(j0 + w*16 + srow) * DKK + scol*16];
                _Float16* ldst = &kv_lds[(w*16 + srow) * KSTR + scol*16];
                *(uint4*)&ldst[0] = *(const uint4*)&gsrc[0];
                *(uint4*)&ldst[8] = *(const uint4*)&gsrc[8];
            }
            __syncthreads();
            {
                const int jbase = j0 + w * 16;
                if (jbase <= r0 + 15) {
                    f32x4 d = {0.f, 0.f, 0.f, 0.f};
                    #pragma unroll
                    for (int ks = 0; ks < 2; ++ks) {
                        half8 a  = *(const half8*)&q_lds[n * QSTR + ks*32 + quad*8];
                        half8 bb = *(const half8*)&kv_lds[(w*16 + n) * KSTR + ks*32 + quad*8];
                        d = __builtin_amdgcn_mfma_f32_16x16x32_f16(a, bb, d, 0, 0, 0);
                    }
                    const int j = jbase + n;
                    #pragma unroll
                    for (int reg = 0; reg < 4; ++reg) {
                        const int i = r0 + quad * 4 + reg;
                        float val = NEGF;
                        if (j <= i)
                            val = d[reg] * 0.125f * utT[((size_t)b * SS + i) * SS + j];
                        s_lds[(quad * 4 + reg) * SSTR + w * 16 + n] = val;
                    }
                } else {
                    #pragma unroll
                    for (int reg = 0; reg < 4; ++reg)
                        s_lds[(quad * 4 + reg) * SSTR + w * 16 + n] = NEGF;
                }
            }
            __syncthreads();
            #pragma unroll
            for (int ttl = 0; ttl < 4; ++ttl)
                sreg[c0 * 4 + ttl] = s_lds[w * SSTR + ttl * 64 + lane];
        }
    }

    // ================= Phase 2: softmax / scan / decay (row = r0+w) =========
    const int i_row = r0 + w;

    float m1 = NEGF;
    #pragma unroll
    for (int t2 = 0; t2 < 16; ++t2) if (t2 < nt) m1 = fmaxf(m1, sreg[t2]);
    #pragma unroll
    for (int o = 32; o >= 1; o >>= 1) m1 = fmaxf(m1, __shfl_xor(m1, o));

    float ee[16];
    float z1 = 0.f;
    #pragma unroll
    for (int t2 = 0; t2 < 16; ++t2) {
        float e = 0.f;
        if (t2 < nt) {
            const int j = t2 * 64 + lane;
            if (j <= i_row) e = __expf(sreg[t2] - m1);
        }
        ee[t2] = e;
        z1 += e;
    }
    #pragma unroll
    for (int o = 32; o >= 1; o >>= 1) z1 += __shfl_xor(z1, o);
    const float inv_z1 = 1.0f / z1;

    const float g     = gammas[h];
    const float gamma = -log1pf(__expf(g));   // -softplus

    float carry = 0.f;
    float m2 = NEGF;
    #pragma unroll
    for (int t2 = 0; t2 < 16; ++t2) {
        if (t2 < nt) {
            float xv = ee[t2];
            #pragma unroll
            for (int o = 1; o < 64; o <<= 1) {
                float y = __shfl_up(xv, (unsigned)o);
                if (lane >= o) xv += y;
            }
            const float tile_tot = __shfl(xv, 63);
            const float csum = (carry + xv) * inv_z1;
            carry += tile_tot;

            const int j = t2 * 64 + lane;
            const float pe = (float)(i_row - j);
            const float dd = fmaxf((1.0f - csum) * pe, 0.0f);
            float te = __expf(sqrtf(dd) * gamma);
            te = fminf(fmaxf(te, 1e-5f), 1e5f);
            const float nsv = (j <= i_row) ? sreg[t2] * te : NEGF;
            ee[t2] = nsv;
            m2 = fmaxf(m2, nsv);
        }
    }
    #pragma unroll
    for (int o = 32; o >= 1; o >>= 1) m2 = fmaxf(m2, __shfl_xor(m2, o));

    float z2 = 0.f;
    #pragma unroll
    for (int t2 = 0; t2 < 16; ++t2) {
        if (t2 < nt) {
            ee[t2] = __expf(ee[t2] - m2);
            z2 += ee[t2];
        }
    }
    #pragma unroll
    for (int o = 32; o >= 1; o >>= 1) z2 += __shfl_xor(z2, o);
    const float inv_z2 = 1.0f / z2;
    #pragma unroll
    for (int t2 = 0; t2 < 16; ++t2) if (t2 < nt) ee[t2] *= inv_z2;

    // ================= Phase 3: PV via MFMA =================
    f32x4 oacc = {0.f, 0.f, 0.f, 0.f};
    #pragma unroll
    for (int c0 = 0; c0 < 4; ++c0) {
        if (c0 < nchunk) {
            const int j0 = c0 * 256;
            __syncthreads();
            {   // stage V j-tile w (fp16 copy, full tile)
                const _Float16* gsrc = &vp[(size_t)(j0 + w*16 + srow) * DKK + scol*16];
                _Float16* ldst = &kv_lds[(w*16 + srow) * VSTR + scol*16];
                *(uint4*)&ldst[0] = *(const uint4*)&gsrc[0];
                *(uint4*)&ldst[8] = *(const uint4*)&gsrc[8];
            }
            #pragma unroll
            for (int ttl = 0; ttl < 4; ++ttl)
                p_lds[w * PSTR + ttl * 64 + lane] = (_Float16)ee[c0 * 4 + ttl];
            __syncthreads();
            if (w < 4) {
                int nkt = (r0 + 16 - j0 + 31) >> 5;
                nkt = (nkt > 8) ? 8 : nkt;   // 1..8
                for (int kt = 0; kt < nkt; ++kt) {
                    half8 a = *(const half8*)&p_lds[n * PSTR + kt * 32 + quad * 8];
                    half8 bb;
                    #pragma unroll
                    for (int jj = 0; jj < 8; ++jj)
                        bb[jj] = kv_lds[(kt * 32 + quad * 8 + jj) * VSTR + w * 16 + n];
                    oacc = __builtin_amdgcn_mfma_f32_16x16x32_f16(a, bb, oacc, 0, 0, 0);
                }
            }
        }
    }

    if (w < 4) {
        #pragma unroll
        for (int reg = 0; reg < 4; ++reg) {
            const int i = r0 + quad * 4 + reg;
            attn[(((size_t)b * SS + i) * HH + h) * DKK + w * 16 + n] = oacc[reg];
        }
    }
}

// ---------------------------------------------------------------------------
extern "C" void kernel_launch(void* const* d_in, const int* in_sizes, int n_in,
                              void* d_out, int out_size, void* d_ws, size_t ws_size,
                              hipStream_t stream) {
    const float* x      = (const float*)d_in[0];
    const float* utT    = (const float*)d_in[1];
    const float* Wk     = (const float*)d_in[2];
    const float* bk     = (const float*)d_in[3];
    const float* Wv     = (const float*)d_in[4];
    const float* bv     = (const float*)d_in[5];
    const float* Wo     = (const float*)d_in[6];
    const float* bo     = (const float*)d_in[7];
    const float* gammas = (const float*)d_in[8];
    float* out = (float*)d_out;

    const size_t per = (size_t)NB * HH * SS * DKK;  // 4,194,304 elements
    _Float16* q_ws   = (_Float16*)d_ws;             // 8 MB
    _Float16* v_ws   = q_ws + per;                  // 8 MB
    float*    attn_ws = (float*)(v_ws + per);       // 16 MB

    dim3 g1(128, 16);
    gemm_qv<<<g1, dim3(256), 0, stream>>>(x, Wk, bk, Wv, bv, q_ws, v_ws);

    dim3 g2(SS / 16, NB * HH);
    attn_mfma<<<g2, dim3(1024), 0, stream>>>(q_ws, v_ws, utT, gammas, attn_ws);

    dim3 g3(128, 8);
    gemm_out<<<g3, dim3(256), 0, stream>>>(attn_ws, Wo, bo, out);
}

// Round 6
// 338.770 us; speedup vs baseline: 2.5206x; 1.2362x over previous
//
#include <hip/hip_runtime.h>
#include <math.h>

#define NB   8
#define SS   1024
#define DD   512
#define HH   8
#define DKK  64
#define NEGF (-3.0e38f)

// LDS strides (elements)
#define QSTR 88    // halves; 176 B rows, 16B-aligned b128 A-frags, 2-way banks (free)
#define SSTR 257   // floats; conflict-free score writes/pulls
#define PSTR 280   // halves; 560 B rows, 16B-aligned b128 A-frags, ~2-way banks
#define WSTR 40    // gemm staging: 80 B rows, 16B-aligned b128 frags

typedef _Float16 half8 __attribute__((ext_vector_type(8)));
typedef float    f32x4 __attribute__((ext_vector_type(4)));

// ---------------------------------------------------------------------------
// MFMA GEMM #1: q = x@Wk^T + bk -> fp16 [b,h,s,dk] ; v = x@Wv^T + bv -> fp16
// TRANSPOSED [b,h,dk,s] (so attn PV B-frags are contiguous b128 loads).
// ---------------------------------------------------------------------------
__global__ __launch_bounds__(256) void gemm_qv(
    const float* __restrict__ x,
    const float* __restrict__ Wk, const float* __restrict__ bk,
    const float* __restrict__ Wv, const float* __restrict__ bv,
    _Float16* __restrict__ q_ws, _Float16* __restrict__ vt_ws)
{
    __shared__ __align__(16) _Float16 Asm[64 * WSTR];
    __shared__ __align__(16) _Float16 Bsm[64 * WSTR];

    const int m0  = blockIdx.x * 64;
    const int n0c = blockIdx.y * 64;          // 0..1023
    const bool is_v = (n0c >= DD);
    const float* __restrict__ Wp = is_v ? Wv : Wk;
    const float* __restrict__ bp = is_v ? bv : bk;
    const int n0 = n0c & (DD - 1);

    const int tid  = threadIdx.x;
    const int w    = tid >> 6;
    const int lane = tid & 63;
    const int quad = lane >> 4;
    const int n    = lane & 15;
    const int wm   = w >> 1, wn = w & 1;

    const int srow = tid >> 2;          // 0..63
    const int sc8  = (tid & 3) * 8;     // 0,8,16,24

    f32x4 acc[2][2] = {{{0.f,0.f,0.f,0.f},{0.f,0.f,0.f,0.f}},
                       {{0.f,0.f,0.f,0.f},{0.f,0.f,0.f,0.f}}};

    for (int k0 = 0; k0 < DD; k0 += 32) {
        __syncthreads();
        {
            const float* src = &x[(size_t)(m0 + srow) * DD + k0 + sc8];
            float4 f0 = *(const float4*)&src[0];
            float4 f1 = *(const float4*)&src[4];
            half8 hv = {(_Float16)f0.x,(_Float16)f0.y,(_Float16)f0.z,(_Float16)f0.w,
                        (_Float16)f1.x,(_Float16)f1.y,(_Float16)f1.z,(_Float16)f1.w};
            *(half8*)&Asm[srow * WSTR + sc8] = hv;
        }
        {
            const float* src = &Wp[(size_t)(n0 + srow) * DD + k0 + sc8];
            float4 f0 = *(const float4*)&src[0];
            float4 f1 = *(const float4*)&src[4];
            half8 hv = {(_Float16)f0.x,(_Float16)f0.y,(_Float16)f0.z,(_Float16)f0.w,
                        (_Float16)f1.x,(_Float16)f1.y,(_Float16)f1.z,(_Float16)f1.w};
            *(half8*)&Bsm[srow * WSTR + sc8] = hv;
        }
        __syncthreads();
        half8 a0 = *(const half8*)&Asm[(wm*32 +  0 + n) * WSTR + quad*8];
        half8 a1 = *(const half8*)&Asm[(wm*32 + 16 + n) * WSTR + quad*8];
        half8 b0 = *(const half8*)&Bsm[(wn*32 +  0 + n) * WSTR + quad*8];
        half8 b1 = *(const half8*)&Bsm[(wn*32 + 16 + n) * WSTR + quad*8];
        acc[0][0] = __builtin_amdgcn_mfma_f32_16x16x32_f16(a0, b0, acc[0][0], 0,0,0);
        acc[0][1] = __builtin_amdgcn_mfma_f32_16x16x32_f16(a0, b1, acc[0][1], 0,0,0);
        acc[1][0] = __builtin_amdgcn_mfma_f32_16x16x32_f16(a1, b0, acc[1][0], 0,0,0);
        acc[1][1] = __builtin_amdgcn_mfma_f32_16x16x32_f16(a1, b1, acc[1][1], 0,0,0);
    }

    const int h = n0 >> 6;   // head (n0 is 64-aligned)
    #pragma unroll
    for (int tm = 0; tm < 2; ++tm) {
        #pragma unroll
        for (int tn = 0; tn < 2; ++tn) {
            const int dk = wn*32 + tn*16 + n;        // 0..63 within head
            const float bias = bp[n0 + dk];
            const int gbase = m0 + wm*32 + tm*16 + quad*4;   // 4 consecutive rows
            const int bidx  = gbase >> 10;
            const int sr    = gbase & (SS - 1);
            if (!is_v) {
                #pragma unroll
                for (int reg = 0; reg < 4; ++reg)
                    q_ws[((size_t)(bidx * HH + h) * SS + sr + reg) * DKK + dk] =
                        (_Float16)(acc[tm][tn][reg] + bias);
            } else {
                _Float16 h4[4];
                #pragma unroll
                for (int reg = 0; reg < 4; ++reg)
                    h4[reg] = (_Float16)(acc[tm][tn][reg] + bias);
                *(uint2*)&vt_ws[((size_t)(bidx * HH + h) * DKK + dk) * SS + sr] =
                    *(uint2*)h4;
            }
        }
    }
}

// ---------------------------------------------------------------------------
// MFMA GEMM #2: out = attn @ Wo^T + bo (A fp32 -> fp16 staged; out fp32)
// ---------------------------------------------------------------------------
__global__ __launch_bounds__(256) void gemm_out(
    const float* __restrict__ A,
    const float* __restrict__ Wo, const float* __restrict__ bo,
    float* __restrict__ out)
{
    __shared__ __align__(16) _Float16 Asm[64 * WSTR];
    __shared__ __align__(16) _Float16 Bsm[64 * WSTR];

    const int m0 = blockIdx.x * 64;
    const int n0 = blockIdx.y * 64;

    const int tid  = threadIdx.x;
    const int w    = tid >> 6;
    const int lane = tid & 63;
    const int quad = lane >> 4;
    const int n    = lane & 15;
    const int wm   = w >> 1, wn = w & 1;

    const int srow = tid >> 2;
    const int sc8  = (tid & 3) * 8;

    f32x4 acc[2][2] = {{{0.f,0.f,0.f,0.f},{0.f,0.f,0.f,0.f}},
                       {{0.f,0.f,0.f,0.f},{0.f,0.f,0.f,0.f}}};

    for (int k0 = 0; k0 < DD; k0 += 32) {
        __syncthreads();
        {
            const float* src = &A[(size_t)(m0 + srow) * DD + k0 + sc8];
            float4 f0 = *(const float4*)&src[0];
            float4 f1 = *(const float4*)&src[4];
            half8 hv = {(_Float16)f0.x,(_Float16)f0.y,(_Float16)f0.z,(_Float16)f0.w,
                        (_Float16)f1.x,(_Float16)f1.y,(_Float16)f1.z,(_Float16)f1.w};
            *(half8*)&Asm[srow * WSTR + sc8] = hv;
        }
        {
            const float* src = &Wo[(size_t)(n0 + srow) * DD + k0 + sc8];
            float4 f0 = *(const float4*)&src[0];
            float4 f1 = *(const float4*)&src[4];
            half8 hv = {(_Float16)f0.x,(_Float16)f0.y,(_Float16)f0.z,(_Float16)f0.w,
                        (_Float16)f1.x,(_Float16)f1.y,(_Float16)f1.z,(_Float16)f1.w};
            *(half8*)&Bsm[srow * WSTR + sc8] = hv;
        }
        __syncthreads();
        half8 a0 = *(const half8*)&Asm[(wm*32 +  0 + n) * WSTR + quad*8];
        half8 a1 = *(const half8*)&Asm[(wm*32 + 16 + n) * WSTR + quad*8];
        half8 b0 = *(const half8*)&Bsm[(wn*32 +  0 + n) * WSTR + quad*8];
        half8 b1 = *(const half8*)&Bsm[(wn*32 + 16 + n) * WSTR + quad*8];
        acc[0][0] = __builtin_amdgcn_mfma_f32_16x16x32_f16(a0, b0, acc[0][0], 0,0,0);
        acc[0][1] = __builtin_amdgcn_mfma_f32_16x16x32_f16(a0, b1, acc[0][1], 0,0,0);
        acc[1][0] = __builtin_amdgcn_mfma_f32_16x16x32_f16(a1, b0, acc[1][0], 0,0,0);
        acc[1][1] = __builtin_amdgcn_mfma_f32_16x16x32_f16(a1, b1, acc[1][1], 0,0,0);
    }

    #pragma unroll
    for (int tm = 0; tm < 2; ++tm) {
        #pragma unroll
        for (int tn = 0; tn < 2; ++tn) {
            const int col  = n0 + wn*32 + tn*16 + n;
            const float bias = bo[col];
            #pragma unroll
            for (int reg = 0; reg < 4; ++reg) {
                const int grow = m0 + wm*32 + tm*16 + quad*4 + reg;
                out[(size_t)grow * DD + col] = acc[tm][tn][reg] + bias;
            }
        }
    }
}

// ---------------------------------------------------------------------------
// MFMA attention, R6: K and V^T fragments loaded DIRECTLY from global (L2-
// resident; LDS staging had zero cross-wave reuse). LDS only for Q (reused
// by all 16 waves), double-buffered score rows, double-buffered P. One
// barrier per chunk per phase.
// ---------------------------------------------------------------------------
__global__ __launch_bounds__(1024) void attn_mfma(
    const _Float16* __restrict__ q,   // [B,H,S,DK] fp16 (K = Q)
    const _Float16* __restrict__ vt,  // [B,H,DK,S] fp16 (V transposed)
    const float* __restrict__ utT,    // [B,S,S]
    const float* __restrict__ gammas, // [H]
    float* __restrict__ attn)         // [B,S,H,DK] fp32
{
    __shared__ __align__(16) float    s_lds[2 * 16 * SSTR];  // 32896 B
    __shared__ __align__(16) _Float16 q_lds[16 * QSTR];      // 2816 B
    _Float16* p_lds = (_Float16*)s_lds;  // phase 3: 2 x 16 x PSTR halves (17920 B)

    const int tid  = threadIdx.x;
    const int w    = tid >> 6;
    const int lane = tid & 63;
    const int quad = lane >> 4;
    const int n    = lane & 15;
    const int bh   = blockIdx.y;
    const int b    = bh >> 3;
    const int h    = bh & 7;
    const int r0   = blockIdx.x * 16;

    const _Float16* __restrict__ kq  = q  + (size_t)bh * SS * DKK;
    const _Float16* __restrict__ vtp = vt + (size_t)bh * DKK * SS;

    const int nchunk = (r0 + 16 + 255) >> 8;   // 1..4, block-uniform
    const int nt     = nchunk * 4;

    // ---- stage Q rows r0..r0+15 (fp16 copy; reused by all 16 waves) ----
    if (tid < 256) {
        const int row = tid >> 4;
        const int c   = tid & 15;
        *(uint2*)&q_lds[row * QSTR + c * 4] =
            *(const uint2*)&kq[(size_t)(r0 + row) * DKK + c * 4];
    }
    __syncthreads();

    float sreg[16];
    #pragma unroll
    for (int t2 = 0; t2 < 16; ++t2) sreg[t2] = NEGF;

    // ================= Phase 1: scores via MFMA (K frags from global) =======
    #pragma unroll
    for (int c0 = 0; c0 < 4; ++c0) {
        if (c0 < nchunk) {
            const int j0  = c0 * 256;
            const int buf = (c0 & 1) * 16 * SSTR;
            const int jbase = j0 + w * 16;
            if (jbase <= r0 + 15) {
                const _Float16* krow = &kq[(size_t)(jbase + n) * DKK];
                half8 b0 = *(const half8*)&krow[quad * 8];
                half8 b1 = *(const half8*)&krow[32 + quad * 8];
                half8 a0 = *(const half8*)&q_lds[n * QSTR + quad * 8];
                half8 a1 = *(const half8*)&q_lds[n * QSTR + 32 + quad * 8];
                f32x4 d = {0.f, 0.f, 0.f, 0.f};
                d = __builtin_amdgcn_mfma_f32_16x16x32_f16(a0, b0, d, 0, 0, 0);
                d = __builtin_amdgcn_mfma_f32_16x16x32_f16(a1, b1, d, 0, 0, 0);
                const int j = jbase + n;
                #pragma unroll
                for (int reg = 0; reg < 4; ++reg) {
                    const int i = r0 + quad * 4 + reg;
                    float val = NEGF;
                    if (j <= i)
                        val = d[reg] * 0.125f * utT[((size_t)b * SS + i) * SS + j];
                    s_lds[buf + (quad * 4 + reg) * SSTR + w * 16 + n] = val;
                }
            } else {
                #pragma unroll
                for (int reg = 0; reg < 4; ++reg)
                    s_lds[buf + (quad * 4 + reg) * SSTR + w * 16 + n] = NEGF;
            }
            __syncthreads();
            #pragma unroll
            for (int ttl = 0; ttl < 4; ++ttl)
                sreg[c0 * 4 + ttl] = s_lds[buf + w * SSTR + ttl * 64 + lane];
        }
    }

    // ================= Phase 2: softmax / scan / decay (row = r0+w) =========
    const int i_row = r0 + w;

    float m1 = NEGF;
    #pragma unroll
    for (int t2 = 0; t2 < 16; ++t2) if (t2 < nt) m1 = fmaxf(m1, sreg[t2]);
    #pragma unroll
    for (int o = 32; o >= 1; o >>= 1) m1 = fmaxf(m1, __shfl_xor(m1, o));

    float ee[16];
    float z1 = 0.f;
    #pragma unroll
    for (int t2 = 0; t2 < 16; ++t2) {
        float e = 0.f;
        if (t2 < nt) {
            const int j = t2 * 64 + lane;
            if (j <= i_row) e = __expf(sreg[t2] - m1);
        }
        ee[t2] = e;
        z1 += e;
    }
    #pragma unroll
    for (int o = 32; o >= 1; o >>= 1) z1 += __shfl_xor(z1, o);
    const float inv_z1 = 1.0f / z1;

    const float g     = gammas[h];
    const float gamma = -log1pf(__expf(g));   // -softplus

    float carry = 0.f;
    float m2 = NEGF;
    #pragma unroll
    for (int t2 = 0; t2 < 16; ++t2) {
        if (t2 < nt) {
            float xv = ee[t2];
            #pragma unroll
            for (int o = 1; o < 64; o <<= 1) {
                float y = __shfl_up(xv, (unsigned)o);
                if (lane >= o) xv += y;
            }
            const float tile_tot = __shfl(xv, 63);
            const float csum = (carry + xv) * inv_z1;
            carry += tile_tot;

            const int j = t2 * 64 + lane;
            const float pe = (float)(i_row - j);
            const float dd = fmaxf((1.0f - csum) * pe, 0.0f);
            float te = __expf(sqrtf(dd) * gamma);
            te = fminf(fmaxf(te, 1e-5f), 1e5f);
            const float nsv = (j <= i_row) ? sreg[t2] * te : NEGF;
            ee[t2] = nsv;
            m2 = fmaxf(m2, nsv);
        }
    }
    #pragma unroll
    for (int o = 32; o >= 1; o >>= 1) m2 = fmaxf(m2, __shfl_xor(m2, o));

    float z2 = 0.f;
    #pragma unroll
    for (int t2 = 0; t2 < 16; ++t2) {
        if (t2 < nt) {
            ee[t2] = __expf(ee[t2] - m2);
            z2 += ee[t2];
        }
    }
    #pragma unroll
    for (int o = 32; o >= 1; o >>= 1) z2 += __shfl_xor(z2, o);
    const float inv_z2 = 1.0f / z2;
    #pragma unroll
    for (int t2 = 0; t2 < 16; ++t2) if (t2 < nt) ee[t2] *= inv_z2;

    __syncthreads();   // phase-3 entry: all s_lds pulls done before p aliases

    // ================= Phase 3: PV via MFMA (V^T frags from global) =========
    f32x4 oacc = {0.f, 0.f, 0.f, 0.f};
    #pragma unroll
    for (int c0 = 0; c0 < 4; ++c0) {
        if (c0 < nchunk) {
            const int j0 = c0 * 256;
            const int pb = (c0 & 1) * 16 * PSTR;
            #pragma unroll
            for (int ttl = 0; ttl < 4; ++ttl)
                p_lds[pb + w * PSTR + ttl * 64 + lane] = (_Float16)ee[c0 * 4 + ttl];
            __syncthreads();
            if (w < 4) {
                int nkt = (r0 + 16 - j0 + 31) >> 5;
                nkt = (nkt > 8) ? 8 : nkt;   // 1..8
                const _Float16* vrow = &vtp[(size_t)(w * 16 + n) * SS + j0];
                for (int kt = 0; kt < nkt; ++kt) {
                    half8 a  = *(const half8*)&p_lds[pb + n * PSTR + kt * 32 + quad * 8];
                    half8 bb = *(const half8*)&vrow[kt * 32 + quad * 8];
                    oacc = __builtin_amdgcn_mfma_f32_16x16x32_f16(a, bb, oacc, 0, 0, 0);
                }
            }
        }
    }

    if (w < 4) {
        #pragma unroll
        for (int reg = 0; reg < 4; ++reg) {
            const int i = r0 + quad * 4 + reg;
            attn[(((size_t)b * SS + i) * HH + h) * DKK + w * 16 + n] = oacc[reg];
        }
    }
}

// ---------------------------------------------------------------------------
extern "C" void kernel_launch(void* const* d_in, const int* in_sizes, int n_in,
                              void* d_out, int out_size, void* d_ws, size_t ws_size,
                              hipStream_t stream) {
    const float* x      = (const float*)d_in[0];
    const float* utT    = (const float*)d_in[1];
    const float* Wk     = (const float*)d_in[2];
    const float* bk     = (const float*)d_in[3];
    const float* Wv     = (const float*)d_in[4];
    const float* bv     = (const float*)d_in[5];
    const float* Wo     = (const float*)d_in[6];
    const float* bo     = (const float*)d_in[7];
    const float* gammas = (const float*)d_in[8];
    float* out = (float*)d_out;

    const size_t per = (size_t)NB * HH * SS * DKK;  // 4,194,304 elements
    _Float16* q_ws   = (_Float16*)d_ws;             // 8 MB, [b,h,s,dk]
    _Float16* vt_ws  = q_ws + per;                  // 8 MB, [b,h,dk,s]
    float*    attn_ws = (float*)(vt_ws + per);      // 16 MB

    dim3 g1(128, 16);
    gemm_qv<<<g1, dim3(256), 0, stream>>>(x, Wk, bk, Wv, bv, q_ws, vt_ws);

    dim3 g2(SS / 16, NB * HH);
    attn_mfma<<<g2, dim3(1024), 0, stream>>>(q_ws, vt_ws, utT, gammas, attn_ws);

    dim3 g3(128, 8);
    gemm_out<<<g3, dim3(256), 0, stream>>>(attn_ws, Wo, bo, out);
}